// Round 2
// baseline (757.111 us; speedup 1.0000x reference)
//
#include <hip/hip_runtime.h>

typedef __attribute__((ext_vector_type(4))) float f32x4;
typedef __attribute__((ext_vector_type(8))) short bf16x8;

#define EPS_ 1e-5f
// SCALE * log2(e): fold exp->exp2 into the q scaling
#define QSC 0.25503639409729144f

// LDS layout (ushort units), total 26624 us = 53248 B -> 3 blocks/CU
#define XS 264      // X / obuf row stride (rows 16B-aligned: 528B = 33*16)
#define SCB 16896   // per-band scratch chunks base
#define CHUNK 1280  // per-band chunk: q[16][40] @0, k[16][40] @640, P[16][72] overlays
#define KOFF 640
#define QSTR 40
#define PSTR 72
#define VTB 22016   // vT double buffer: 2 x [32][72]
#define VTSZ 2304

__device__ __forceinline__ unsigned int pack2(float a, float b) {
  union { float f; unsigned int u; } ua, ub;
  ua.f = a; ub.f = b;
  unsigned int ra = (ua.u + 0x7FFFu + ((ua.u >> 16) & 1u)) >> 16;
  unsigned int rb = (ub.u + 0x7FFFu + ((ub.u >> 16) & 1u)) & 0xFFFF0000u;
  return ra | rb;
}
__device__ __forceinline__ uint2 pack4(f32x4 v) {
  uint2 o; o.x = pack2(v[0], v[1]); o.y = pack2(v[2], v[3]); return o;
}
__device__ __forceinline__ unsigned short f2b(float f) {
  union { float f; unsigned int u; } c; c.f = f;
  return (unsigned short)((c.u + 0x7FFFu + ((c.u >> 16) & 1u)) >> 16);
}

// K0: fp32 weights -> bf16, 4 matrices of 256x256, concatenated [Wq|Wk|Wv|Wp].
__global__ __launch_bounds__(256) void k0_cvt(const float* __restrict__ w0,
                                              const float* __restrict__ w1,
                                              const float* __restrict__ w2,
                                              const float* __restrict__ w3,
                                              unsigned short* __restrict__ dst) {
  int idx = blockIdx.x * 256 + threadIdx.x;
  const float* s = (blockIdx.y == 0) ? w0 : (blockIdx.y == 1) ? w1 : (blockIdx.y == 2) ? w2 : w3;
  dst[blockIdx.y * 65536 + idx] = f2b(s[idx]);
}

// KA: fully fused LN + gather + window attention + projection + scatter residual.
// Block = 256 threads (4 waves) = 1 window. Wave owns token band [wv*16, wv*16+16).
__global__ __launch_bounds__(256, 3) void ka_fused(
    const float* __restrict__ inpt, const int* __restrict__ pn, const int* __restrict__ pt,
    const float* __restrict__ g, const float* __restrict__ be,
    const unsigned short* __restrict__ Wall,
    const float* __restrict__ bq, const float* __restrict__ bk,
    const float* __restrict__ bv, const float* __restrict__ bp,
    float* __restrict__ out) {
  __shared__ unsigned short lds[26624];
  const int tid = threadIdx.x;
  const int wv = tid >> 6, lane = tid & 63, quad = lane >> 4, l15 = lane & 15;
  const int w = blockIdx.x;
  const int b = w >> 9, nbb = (w >> 6) & 7, tbb = w & 63;

  // token -> global row offset table, stashed in X rows' 16B pad (col 256..263)
  if (tid < 64) {
    const int n = (nbb << 3) + (tid >> 3), t = (tbb << 3) + (tid & 7);
    const int off = (((b << 6) + pn[(b << 6) + n]) * 512 + pt[(b << 9) + t]) * 256;
    *(int*)(lds + tid * XS + 256) = off;
  }
  __syncthreads();

  // ---- LN + gather: own band -> X (bf16, band-private) ----
  {
    float4 gg = ((const float4*)g)[lane];
    float4 bb = ((const float4*)be)[lane];
    for (int c = 0; c < 4; ++c) {
      float4 v[4];
      int row[4];
      #pragma unroll
      for (int i = 0; i < 4; ++i) {
        row[i] = wv * 16 + c * 4 + i;
        const int off = *(const int*)(lds + row[i] * XS + 256);
        v[i] = ((const float4*)(inpt + off))[lane];
      }
      #pragma unroll
      for (int i = 0; i < 4; ++i) {
        float s = v[i].x + v[i].y + v[i].z + v[i].w;
        float ss = v[i].x * v[i].x + v[i].y * v[i].y + v[i].z * v[i].z + v[i].w * v[i].w;
        #pragma unroll
        for (int m = 1; m < 64; m <<= 1) { s += __shfl_xor(s, m); ss += __shfl_xor(ss, m); }
        const float mean = s * (1.0f / 256.0f);
        const float rs = rsqrtf(ss * (1.0f / 256.0f) - mean * mean + EPS_);
        f32x4 o;
        o[0] = (v[i].x - mean) * rs * gg.x + bb.x;
        o[1] = (v[i].y - mean) * rs * gg.y + bb.y;
        o[2] = (v[i].z - mean) * rs * gg.z + bb.z;
        o[3] = (v[i].w - mean) * rs * gg.w + bb.w;
        *(uint2*)(lds + row[i] * XS + lane * 4) = pack4(o);
      }
    }
  }
  // no barrier needed: X is only ever read band-private until proj (which barriers)

  const unsigned short* Wq = Wall;
  const unsigned short* Wk = Wall + 65536;
  const unsigned short* Wv_ = Wall + 131072;
  const unsigned short* Wp = Wall + 196608;
  unsigned short* chunk = lds + SCB + wv * CHUNK;
  const f32x4 z4 = {0.f, 0.f, 0.f, 0.f};

  uint2 opk[8][2];  // packed bf16 O^T fragments per head

  for (int h = 0; h < 8; ++h) {
    unsigned short* vT = lds + VTB + (h & 1) * VTSZ;

    // ---- QKV for head h (band-cooperative): Q^T,K^T = W·X^T ; V = X·W^T ----
    f32x4 aq[2] = {z4, z4}, ak[2] = {z4, z4}, av[2] = {z4, z4};
    #pragma unroll
    for (int ks = 0; ks < 8; ++ks) {
      bf16x8 bx = *(const bf16x8*)(lds + (wv * 16 + l15) * XS + ks * 32 + quad * 8);
      #pragma unroll
      for (int m2 = 0; m2 < 2; ++m2) {
        const int wrow = (h * 32 + m2 * 16 + l15) * 256 + ks * 32 + quad * 8;
        bf16x8 wq8 = *(const bf16x8*)(Wq + wrow);
        bf16x8 wk8 = *(const bf16x8*)(Wk + wrow);
        bf16x8 wv8 = *(const bf16x8*)(Wv_ + wrow);
        aq[m2] = __builtin_amdgcn_mfma_f32_16x16x32_bf16(wq8, bx, aq[m2], 0, 0, 0);
        ak[m2] = __builtin_amdgcn_mfma_f32_16x16x32_bf16(wk8, bx, ak[m2], 0, 0, 0);
        av[m2] = __builtin_amdgcn_mfma_f32_16x16x32_bf16(bx, wv8, av[m2], 0, 0, 0);
      }
    }
    // packed stores: q/k rows = own qtok band (col=l15), v -> vT[ch][tok] (col=ch)
    #pragma unroll
    for (int m2 = 0; m2 < 2; ++m2) {
      float4 bq4 = ((const float4*)(bq + h * 32 + m2 * 16))[quad];
      float4 bk4 = ((const float4*)(bk + h * 32 + m2 * 16))[quad];
      f32x4 qv, kv;
      qv[0] = (aq[m2][0] + bq4.x) * QSC; kv[0] = ak[m2][0] + bk4.x;
      qv[1] = (aq[m2][1] + bq4.y) * QSC; kv[1] = ak[m2][1] + bk4.y;
      qv[2] = (aq[m2][2] + bq4.z) * QSC; kv[2] = ak[m2][2] + bk4.z;
      qv[3] = (aq[m2][3] + bq4.w) * QSC; kv[3] = ak[m2][3] + bk4.w;
      *(uint2*)(chunk + l15 * QSTR + m2 * 16 + quad * 4) = pack4(qv);
      *(uint2*)(chunk + KOFF + l15 * QSTR + m2 * 16 + quad * 4) = pack4(kv);
      const float bvv = bv[h * 32 + m2 * 16 + l15];
      f32x4 vv;
      vv[0] = av[m2][0] + bvv; vv[1] = av[m2][1] + bvv;
      vv[2] = av[m2][2] + bvv; vv[3] = av[m2][3] + bvv;
      *(uint2*)(vT + (m2 * 16 + l15) * PSTR + wv * 16 + quad * 4) = pack4(vv);
    }
    __syncthreads();  // bar1: k (all bands) + vT ready

    // ---- S^T = k·q^T (own 16 q-cols), K=32 single MFMA per tile ----
    bf16x8 qf = *(const bf16x8*)(chunk + l15 * QSTR + quad * 8);
    f32x4 st[4];
    #pragma unroll
    for (int mtk = 0; mtk < 4; ++mtk) {
      bf16x8 kf = *(const bf16x8*)(lds + SCB + mtk * CHUNK + KOFF + l15 * QSTR + quad * 8);
      st[mtk] = __builtin_amdgcn_mfma_f32_16x16x32_bf16(kf, qf, z4, 0, 0, 0);
    }
    // softmax over ktok (exp2, no max-subtract: |S*log2e| << 1 by construction)
    float sm = 0.f;
    #pragma unroll
    for (int mtk = 0; mtk < 4; ++mtk) {
      #pragma unroll
      for (int r = 0; r < 4; ++r) { const float e = exp2f(st[mtk][r]); st[mtk][r] = e; sm += e; }
    }
    sm += __shfl_xor(sm, 16);
    sm += __shfl_xor(sm, 32);
    const float inv = 1.0f / sm;
    __syncthreads();  // bar2: all waves' q/k reads done before P overlays them

    #pragma unroll
    for (int mtk = 0; mtk < 4; ++mtk) {
      f32x4 pv;
      pv[0] = st[mtk][0] * inv; pv[1] = st[mtk][1] * inv;
      pv[2] = st[mtk][2] * inv; pv[3] = st[mtk][3] * inv;
      *(uint2*)(chunk + l15 * PSTR + mtk * 16 + quad * 4) = pack4(pv);
    }

    // ---- O^T = V^T · P^T (own 16 q-cols), K=64 ----
    f32x4 oa[2] = {z4, z4};
    #pragma unroll
    for (int kk = 0; kk < 2; ++kk) {
      bf16x8 pb = *(const bf16x8*)(chunk + l15 * PSTR + kk * 32 + quad * 8);
      #pragma unroll
      for (int m2 = 0; m2 < 2; ++m2) {
        bf16x8 vf = *(const bf16x8*)(vT + (m2 * 16 + l15) * PSTR + kk * 32 + quad * 8);
        oa[m2] = __builtin_amdgcn_mfma_f32_16x16x32_bf16(vf, pb, oa[m2], 0, 0, 0);
      }
    }
    opk[h][0] = pack4(oa[0]);
    opk[h][1] = pack4(oa[1]);
  }

  // ---- O^T -> obuf (overlays X, band-private rows) ----
  #pragma unroll
  for (int h = 0; h < 8; ++h)
    #pragma unroll
    for (int m2 = 0; m2 < 2; ++m2)
      *(uint2*)(lds + (wv * 16 + l15) * XS + h * 32 + m2 * 16 + quad * 4) = opk[h][m2];
  __syncthreads();

  // ---- proj^T = Wp · O^T : wave owns 64 out-channels ----
  f32x4 pacc[4][4];
  #pragma unroll
  for (int mto = 0; mto < 4; ++mto)
    #pragma unroll
    for (int nto = 0; nto < 4; ++nto) pacc[mto][nto] = z4;
  #pragma unroll
  for (int ks = 0; ks < 8; ++ks) {
    bf16x8 ob[4];
    #pragma unroll
    for (int nto = 0; nto < 4; ++nto)
      ob[nto] = *(const bf16x8*)(lds + (nto * 16 + l15) * XS + ks * 32 + quad * 8);
    #pragma unroll
    for (int mto = 0; mto < 4; ++mto) {
      bf16x8 wp8 = *(const bf16x8*)(Wp + (wv * 64 + mto * 16 + l15) * 256 + ks * 32 + quad * 8);
      #pragma unroll
      for (int nto = 0; nto < 4; ++nto)
        pacc[mto][nto] = __builtin_amdgcn_mfma_f32_16x16x32_bf16(wp8, ob[nto], pacc[mto][nto], 0, 0, 0);
    }
  }

  // ---- epilogue: +bp, residual, coalesced float4 scatter ----
  #pragma unroll
  for (int mto = 0; mto < 4; ++mto) {
    float4 bp4 = ((const float4*)(bp + wv * 64 + mto * 16))[quad];
    #pragma unroll
    for (int nto = 0; nto < 4; ++nto) {
      const int tok = nto * 16 + l15;
      const int off = *(const int*)(lds + tok * XS + 256) + wv * 64 + mto * 16 + quad * 4;
      float4 iv = *(const float4*)(inpt + off);
      float4 o;
      o.x = iv.x + pacc[mto][nto][0] + bp4.x;
      o.y = iv.y + pacc[mto][nto][1] + bp4.y;
      o.z = iv.z + pacc[mto][nto][2] + bp4.z;
      o.w = iv.w + pacc[mto][nto][3] + bp4.w;
      *(float4*)(out + off) = o;
    }
  }
}

extern "C" void kernel_launch(void* const* d_in, const int* in_sizes, int n_in,
                              void* d_out, int out_size, void* d_ws, size_t ws_size,
                              hipStream_t stream) {
  const float* inpt = (const float*)d_in[0];
  const int* perm_n = (const int*)d_in[1];
  const int* perm_t = (const int*)d_in[2];
  const float* ln_g = (const float*)d_in[3];
  const float* ln_b = (const float*)d_in[4];
  const float* Wq = (const float*)d_in[5];
  const float* bq = (const float*)d_in[6];
  const float* Wk = (const float*)d_in[7];
  const float* bk = (const float*)d_in[8];
  const float* Wv = (const float*)d_in[9];
  const float* bv = (const float*)d_in[10];
  const float* Wp = (const float*)d_in[11];
  const float* bp = (const float*)d_in[12];
  float* out = (float*)d_out;

  unsigned short* Wall = (unsigned short*)d_ws;  // 4 * 65536 bf16 = 512 KiB

  k0_cvt<<<dim3(256, 4), 256, 0, stream>>>(Wq, Wk, Wv, Wp, Wall);
  ka_fused<<<2048, 256, 0, stream>>>(inpt, perm_n, perm_t, ln_g, ln_b, Wall,
                                     bq, bk, bv, bp, out);
}

// Round 3
// 488.899 us; speedup vs baseline: 1.5486x; 1.5486x over previous
//
#include <hip/hip_runtime.h>

typedef __attribute__((ext_vector_type(4))) float f32x4;
typedef __attribute__((ext_vector_type(8))) short bf16x8;

#define EPS_ 1e-5f
// SCALE * log2(e): fold exp -> exp2 into the q scaling
#define QSC 0.25503639409729144f

// Dynamic LDS layout (ushort units):
// X/obuf  [64][264]            @0      (16896 us)  rows 528B: bank stride 4 -> 2-way, free
// chunks  8 x 7424             @16896  (59392 us)
//   per-wave chunk: q[64][40] @0, k[64][40] @2560 (P[64][72] overlays q+k), vT[32][72] @5120
// tok_off int[64]              @76288us (byte 152576)
#define XS 264
#define SCB 16896
#define CHUNK 7424
#define QSTR 40
#define KOFF 2560
#define PSTR 72
#define VTOFF 5120
#define VSTR 72
#define LDS_US 76288
#define LDS_BYTES (LDS_US * 2 + 256)

__device__ __forceinline__ unsigned int pack2(float a, float b) {
  union { float f; unsigned int u; } ua, ub;
  ua.f = a; ub.f = b;
  unsigned int ra = (ua.u + 0x7FFFu + ((ua.u >> 16) & 1u)) >> 16;
  unsigned int rb = (ub.u + 0x7FFFu + ((ub.u >> 16) & 1u)) & 0xFFFF0000u;
  return ra | rb;
}
__device__ __forceinline__ uint2 pack4(f32x4 v) {
  uint2 o; o.x = pack2(v[0], v[1]); o.y = pack2(v[2], v[3]); return o;
}
__device__ __forceinline__ unsigned short f2b(float f) {
  union { float f; unsigned int u; } c; c.f = f;
  return (unsigned short)((c.u + 0x7FFFu + ((c.u >> 16) & 1u)) >> 16);
}

// K0: fp32 weights -> bf16, [Wq|Wk|Wv|Wp] each 256x256.
__global__ __launch_bounds__(256) void k0_cvt(const float* __restrict__ w0,
                                              const float* __restrict__ w1,
                                              const float* __restrict__ w2,
                                              const float* __restrict__ w3,
                                              unsigned short* __restrict__ dst) {
  int idx = blockIdx.x * 256 + threadIdx.x;
  const float* s = (blockIdx.y == 0) ? w0 : (blockIdx.y == 1) ? w1 : (blockIdx.y == 2) ? w2 : w3;
  dst[blockIdx.y * 65536 + idx] = f2b(s[idx]);
}

// K1: LayerNorm + permutation gather + window partition -> Xg[w][l][c] bf16.
// One wave = 4 consecutive tokens (same b,n; t0..t0+3 never crosses a T-row).
__global__ __launch_bounds__(256) void k1_ln(const float* __restrict__ x,
                                             const int* __restrict__ pn,
                                             const int* __restrict__ pt,
                                             const float* __restrict__ g,
                                             const float* __restrict__ be,
                                             unsigned short* __restrict__ Xg) {
  const int wave = threadIdx.x >> 6, lane = threadIdx.x & 63;
  const int tok0 = (blockIdx.x * 4 + wave) * 4;      // 0..131068
  const int b = tok0 >> 15, rem = tok0 & 32767;
  const int n = rem >> 9, t0 = rem & 511;
  const int spn = pn[(b << 6) + n];
  const float* rowbase = x + (size_t)(((b << 6) + spn) * 512) * 256;
  float4 gg = ((const float4*)g)[lane];
  float4 bb = ((const float4*)be)[lane];
  float4 v[4];
  int wl[4];
  #pragma unroll
  for (int i = 0; i < 4; ++i) {
    const int t = t0 + i;
    const int spt = pt[(b << 9) + t];
    v[i] = ((const float4*)(rowbase + spt * 256))[lane];
    const int w = ((b << 3) + (n >> 3)) * 64 + (t >> 3);
    const int l = ((n & 7) << 3) + (t & 7);
    wl[i] = (w << 6) + l;
  }
  #pragma unroll
  for (int i = 0; i < 4; ++i) {
    float s = v[i].x + v[i].y + v[i].z + v[i].w;
    float ss = v[i].x * v[i].x + v[i].y * v[i].y + v[i].z * v[i].z + v[i].w * v[i].w;
    #pragma unroll
    for (int m = 1; m < 64; m <<= 1) { s += __shfl_xor(s, m); ss += __shfl_xor(ss, m); }
    const float mean = s * (1.0f / 256.0f);
    const float rs = rsqrtf(ss * (1.0f / 256.0f) - mean * mean + EPS_);
    ushort4 o;
    o.x = f2b((v[i].x - mean) * rs * gg.x + bb.x);
    o.y = f2b((v[i].y - mean) * rs * gg.y + bb.y);
    o.z = f2b((v[i].z - mean) * rs * gg.z + bb.z);
    o.w = f2b((v[i].w - mean) * rs * gg.w + bb.w);
    ((ushort4*)(Xg + (size_t)wl[i] * 256))[lane] = o;
  }
}

// KA: one window per 512-thread block; wave wv owns head wv entirely (wave-private
// attention, no barriers between QKV/S/softmax/PV). 3 barriers total.
__global__ __launch_bounds__(512, 2) void ka_fused(
    const unsigned short* __restrict__ Xg, const unsigned short* __restrict__ Wall,
    const float* __restrict__ pn_, const float* __restrict__ pt_,  // unused (typed slots)
    const int* __restrict__ pn, const int* __restrict__ pt,
    const float* __restrict__ bq, const float* __restrict__ bk,
    const float* __restrict__ bv, const float* __restrict__ bp,
    const float* __restrict__ inpt, float* __restrict__ out) {
  extern __shared__ unsigned short lds[];
  int* tok_off = (int*)(lds + LDS_US);

  const int tid = threadIdx.x;
  const int wv = tid >> 6, lane = tid & 63, quad = lane >> 4, l15 = lane & 15;
  const int w = blockIdx.x;
  const f32x4 z4 = {0.f, 0.f, 0.f, 0.f};

  if (tid < 64) {
    const int b = w >> 9, nbb = (w >> 6) & 7, tbb = w & 63;
    const int n = (nbb << 3) + (tid >> 3), t = (tbb << 3) + (tid & 7);
    tok_off[tid] = (((b << 6) + pn[(b << 6) + n]) * 512 + pt[(b << 9) + t]) * 256;
  }
  // stage X tile (32KB contiguous) into padded LDS rows
  {
    const unsigned short* src = Xg + (size_t)w * 16384;
    #pragma unroll
    for (int i = 0; i < 4; ++i) {
      const int idx = tid + i * 512;            // 16B-chunk index 0..2047
      const int row = idx >> 5, c = idx & 31;
      *(uint4*)(lds + row * XS + c * 8) = *(const uint4*)(src + row * 256 + c * 8);
    }
  }
  __syncthreads();

  const unsigned short* Wq = Wall;
  const unsigned short* Wk = Wall + 65536;
  const unsigned short* Wv_ = Wall + 131072;
  const unsigned short* Wp = Wall + 196608;
  unsigned short* chunk = lds + SCB + wv * CHUNK;
  const int h = wv;

  // ---- QKV for head h: Q^T,K^T = W·X^T (A=W rows=ch, B=X rows=tok); V = X·Wv^T ----
  f32x4 qa[2][4], ka_[2][4], va[4][2];
  #pragma unroll
  for (int m2 = 0; m2 < 2; ++m2)
    #pragma unroll
    for (int nt = 0; nt < 4; ++nt) { qa[m2][nt] = z4; ka_[m2][nt] = z4; }
  #pragma unroll
  for (int mt = 0; mt < 4; ++mt)
    #pragma unroll
    for (int m2 = 0; m2 < 2; ++m2) va[mt][m2] = z4;

  #pragma unroll
  for (int ks = 0; ks < 8; ++ks) {
    bf16x8 bx[4];
    #pragma unroll
    for (int nt = 0; nt < 4; ++nt)
      bx[nt] = *(const bf16x8*)(lds + (nt * 16 + l15) * XS + ks * 32 + quad * 8);
    #pragma unroll
    for (int m2 = 0; m2 < 2; ++m2) {
      const int wrow = (h * 32 + m2 * 16 + l15) * 256 + ks * 32 + quad * 8;
      bf16x8 wq8 = *(const bf16x8*)(Wq + wrow);
      bf16x8 wk8 = *(const bf16x8*)(Wk + wrow);
      bf16x8 wv8 = *(const bf16x8*)(Wv_ + wrow);
      #pragma unroll
      for (int nt = 0; nt < 4; ++nt) {
        qa[m2][nt] = __builtin_amdgcn_mfma_f32_16x16x32_bf16(wq8, bx[nt], qa[m2][nt], 0, 0, 0);
        ka_[m2][nt] = __builtin_amdgcn_mfma_f32_16x16x32_bf16(wk8, bx[nt], ka_[m2][nt], 0, 0, 0);
        va[nt][m2] = __builtin_amdgcn_mfma_f32_16x16x32_bf16(bx[nt], wv8, va[nt][m2], 0, 0, 0);
      }
    }
  }

  // stores: q/k rows=tok (col=l15), packed over ch; vT rows=ch, packed over tok
  #pragma unroll
  for (int m2 = 0; m2 < 2; ++m2) {
    float4 bq4 = ((const float4*)(bq + h * 32 + m2 * 16))[quad];
    float4 bk4 = ((const float4*)(bk + h * 32 + m2 * 16))[quad];
    #pragma unroll
    for (int nt = 0; nt < 4; ++nt) {
      f32x4 qv, kv;
      qv[0] = (qa[m2][nt][0] + bq4.x) * QSC; kv[0] = ka_[m2][nt][0] + bk4.x;
      qv[1] = (qa[m2][nt][1] + bq4.y) * QSC; kv[1] = ka_[m2][nt][1] + bk4.y;
      qv[2] = (qa[m2][nt][2] + bq4.z) * QSC; kv[2] = ka_[m2][nt][2] + bk4.z;
      qv[3] = (qa[m2][nt][3] + bq4.w) * QSC; kv[3] = ka_[m2][nt][3] + bk4.w;
      *(uint2*)(chunk + (nt * 16 + l15) * QSTR + m2 * 16 + quad * 4) = pack4(qv);
      *(uint2*)(chunk + KOFF + (nt * 16 + l15) * QSTR + m2 * 16 + quad * 4) = pack4(kv);
    }
    const float bvv = bv[h * 32 + m2 * 16 + l15];
    #pragma unroll
    for (int mt = 0; mt < 4; ++mt) {
      f32x4 vv;
      vv[0] = va[mt][m2][0] + bvv; vv[1] = va[mt][m2][1] + bvv;
      vv[2] = va[mt][m2][2] + bvv; vv[3] = va[mt][m2][3] + bvv;
      *(uint2*)(chunk + VTOFF + (m2 * 16 + l15) * VSTR + mt * 16 + quad * 4) = pack4(vv);
    }
  }

  // ---- S^T = k·q^T (col=qtok, row=ktok), K=32 ----
  bf16x8 qf[4], kf[4];
  #pragma unroll
  for (int i = 0; i < 4; ++i) {
    qf[i] = *(const bf16x8*)(chunk + (i * 16 + l15) * QSTR + quad * 8);
    kf[i] = *(const bf16x8*)(chunk + KOFF + (i * 16 + l15) * QSTR + quad * 8);
  }
  f32x4 st[4][4];  // [mtk][ntq]
  #pragma unroll
  for (int mtk = 0; mtk < 4; ++mtk)
    #pragma unroll
    for (int ntq = 0; ntq < 4; ++ntq)
      st[mtk][ntq] = __builtin_amdgcn_mfma_f32_16x16x32_bf16(kf[mtk], qf[ntq], z4, 0, 0, 0);

  // softmax over ktok (VALU sums + 2 swizzles per qtok-tile; exp2, no max-subtract)
  float inv[4];
  #pragma unroll
  for (int ntq = 0; ntq < 4; ++ntq) {
    float tot = 0.f;
    #pragma unroll
    for (int mtk = 0; mtk < 4; ++mtk)
      #pragma unroll
      for (int r = 0; r < 4; ++r) {
        const float e = __builtin_amdgcn_exp2f(st[mtk][ntq][r]);
        st[mtk][ntq][r] = e; tot += e;
      }
    tot += __shfl_xor(tot, 16);
    tot += __shfl_xor(tot, 32);
    inv[ntq] = 1.0f / tot;
  }
  // P[qtok][ktok] (overlays q+k region; qf/kf already in regs)
  #pragma unroll
  for (int ntq = 0; ntq < 4; ++ntq)
    #pragma unroll
    for (int mtk = 0; mtk < 4; ++mtk) {
      f32x4 pv;
      pv[0] = st[mtk][ntq][0] * inv[ntq]; pv[1] = st[mtk][ntq][1] * inv[ntq];
      pv[2] = st[mtk][ntq][2] * inv[ntq]; pv[3] = st[mtk][ntq][3] * inv[ntq];
      *(uint2*)(chunk + (ntq * 16 + l15) * PSTR + mtk * 16 + quad * 4) = pack4(pv);
    }

  // ---- O^T = V^T·P^T (A=vT rows=ch, B=P rows=qtok), K=64 ----
  f32x4 oa[2][4];
  #pragma unroll
  for (int m2 = 0; m2 < 2; ++m2)
    #pragma unroll
    for (int ntq = 0; ntq < 4; ++ntq) oa[m2][ntq] = z4;
  #pragma unroll
  for (int kk = 0; kk < 2; ++kk) {
    bf16x8 pb[4], vf[2];
    #pragma unroll
    for (int ntq = 0; ntq < 4; ++ntq)
      pb[ntq] = *(const bf16x8*)(chunk + (ntq * 16 + l15) * PSTR + kk * 32 + quad * 8);
    #pragma unroll
    for (int m2 = 0; m2 < 2; ++m2)
      vf[m2] = *(const bf16x8*)(chunk + VTOFF + (m2 * 16 + l15) * VSTR + kk * 32 + quad * 8);
    #pragma unroll
    for (int m2 = 0; m2 < 2; ++m2)
      #pragma unroll
      for (int ntq = 0; ntq < 4; ++ntq)
        oa[m2][ntq] = __builtin_amdgcn_mfma_f32_16x16x32_bf16(vf[m2], pb[ntq], oa[m2][ntq], 0, 0, 0);
  }
  uint2 opk[2][4];
  #pragma unroll
  for (int m2 = 0; m2 < 2; ++m2)
    #pragma unroll
    for (int ntq = 0; ntq < 4; ++ntq) opk[m2][ntq] = pack4(oa[m2][ntq]);

  __syncthreads();  // all waves done reading X
  #pragma unroll
  for (int m2 = 0; m2 < 2; ++m2)
    #pragma unroll
    for (int ntq = 0; ntq < 4; ++ntq)
      *(uint2*)(lds + (ntq * 16 + l15) * XS + h * 32 + m2 * 16 + quad * 4) = opk[m2][ntq];
  __syncthreads();  // obuf ready

  // ---- proj^T = Wp·O^T : wave owns out-channels [wv*32, wv*32+32) ----
  f32x4 pacc[2][4];
  #pragma unroll
  for (int m2 = 0; m2 < 2; ++m2)
    #pragma unroll
    for (int nto = 0; nto < 4; ++nto) pacc[m2][nto] = z4;
  #pragma unroll
  for (int ks = 0; ks < 8; ++ks) {
    bf16x8 ob[4];
    #pragma unroll
    for (int nto = 0; nto < 4; ++nto)
      ob[nto] = *(const bf16x8*)(lds + (nto * 16 + l15) * XS + ks * 32 + quad * 8);
    #pragma unroll
    for (int m2 = 0; m2 < 2; ++m2) {
      bf16x8 wp8 = *(const bf16x8*)(Wp + (wv * 32 + m2 * 16 + l15) * 256 + ks * 32 + quad * 8);
      #pragma unroll
      for (int nto = 0; nto < 4; ++nto)
        pacc[m2][nto] = __builtin_amdgcn_mfma_f32_16x16x32_bf16(wp8, ob[nto], pacc[m2][nto], 0, 0, 0);
    }
  }

  // ---- epilogue: +bp, residual, float4 scatter (col=tok, row=och) ----
  #pragma unroll
  for (int m2 = 0; m2 < 2; ++m2) {
    float4 bp4 = ((const float4*)(bp + wv * 32 + m2 * 16))[quad];
    #pragma unroll
    for (int nto = 0; nto < 4; ++nto) {
      const int tok = nto * 16 + l15;
      const int off = tok_off[tok] + wv * 32 + m2 * 16 + quad * 4;
      float4 iv = *(const float4*)(inpt + off);
      float4 o;
      o.x = iv.x + pacc[m2][nto][0] + bp4.x;
      o.y = iv.y + pacc[m2][nto][1] + bp4.y;
      o.z = iv.z + pacc[m2][nto][2] + bp4.z;
      o.w = iv.w + pacc[m2][nto][3] + bp4.w;
      *(float4*)(out + off) = o;
    }
  }
}

extern "C" void kernel_launch(void* const* d_in, const int* in_sizes, int n_in,
                              void* d_out, int out_size, void* d_ws, size_t ws_size,
                              hipStream_t stream) {
  const float* inpt = (const float*)d_in[0];
  const int* perm_n = (const int*)d_in[1];
  const int* perm_t = (const int*)d_in[2];
  const float* ln_g = (const float*)d_in[3];
  const float* ln_b = (const float*)d_in[4];
  const float* Wq = (const float*)d_in[5];
  const float* bq = (const float*)d_in[6];
  const float* Wk = (const float*)d_in[7];
  const float* bk = (const float*)d_in[8];
  const float* Wv = (const float*)d_in[9];
  const float* bv = (const float*)d_in[10];
  const float* Wp = (const float*)d_in[11];
  const float* bp = (const float*)d_in[12];
  float* out = (float*)d_out;

  // ws: Xg (2048*64*256 bf16 = 64 MiB) | Wall (512 KiB)
  unsigned short* Xg = (unsigned short*)d_ws;
  unsigned short* Wall = (unsigned short*)((char*)d_ws + (size_t)67108864);

  (void)hipFuncSetAttribute((const void*)ka_fused,
                            hipFuncAttributeMaxDynamicSharedMemorySize, LDS_BYTES);

  k0_cvt<<<dim3(256, 4), 256, 0, stream>>>(Wq, Wk, Wv, Wp, Wall);
  k1_ln<<<8192, 256, 0, stream>>>(inpt, perm_n, perm_t, ln_g, ln_b, Xg);
  ka_fused<<<2048, 512, LDS_BYTES, stream>>>(Xg, Wall, nullptr, nullptr, perm_n, perm_t,
                                             bq, bk, bv, bp, inpt, out);
}